// Round 18
// baseline (37.675 us; speedup 1.0000x reference)
//
#include <hip/hip_runtime.h>

// Problem constants (match reference setup_inputs)
#define NB 8
#define NM 64
#define NA 49104
#define NC 80
#define EPSF 1e-4f
#define ANCB 192   // anchor-role blocks per image (first in dispatch order)
#define STRB 256   // stream-role blocks per image

// Per-block partials; every slot written unconditionally -> no memset needed.
struct Ws {
    float negp[NB][STRB];
    float corrp[NB][ANCB];
    float regp[NB][ANCB];
    float npp[NB][ANCB];
};

__device__ __forceinline__ float waveReduceSumF(float v) {
    #pragma unroll
    for (int off = 32; off > 0; off >>= 1) v += __shfl_down(v, off, 64);
    return v;
}

// Slim neg term: S = sum v^2 * log2(max(1-v, eps)); contribution -0.75*ln2*S.
#define NEG_SCALE (-0.51986038542f)   // -(0.75 * ln 2)

#define CONSUME4(V)                                                   \
    s0 = fmaf((V).x * (V).x, __log2f(fmaxf(1.0f - (V).x, EPSF)), s0); \
    s1 = fmaf((V).y * (V).y, __log2f(fmaxf(1.0f - (V).y, EPSF)), s1); \
    s2 = fmaf((V).z * (V).z, __log2f(fmaxf(1.0f - (V).z, EPSF)), s2); \
    s3 = fmaf((V).w * (V).w, __log2f(fmaxf(1.0f - (V).w, EPSF)), s3);

// Role-split fused kernel. bx < ANCB -> anchor role (pure VALU after
// s_loads); else stream role (pure BW). Anchor blocks dispatch first,
// retire in ~6us, and free CU slots for the remaining stream blocks;
// while resident they co-schedule with stream waves on the same CUs
// (VALU and memory pipes overlap across waves). No wave runs both
// phases serially -- this is the overlap R10/R15/R17's intra-block
// reordering could not achieve.
__global__ void main_kernel(const float4* __restrict__ cls4,
                            const float* __restrict__ cls,
                            const float4* __restrict__ anchors4,
                            const float4* __restrict__ reg,
                            const float4* __restrict__ boxes4,
                            const int* __restrict__ labels,
                            Ws* __restrict__ ws) {
    const int j = blockIdx.y;
    const int bx = blockIdx.x;
    const int tid = threadIdx.x;
    __shared__ float sred[3][4];

    if (bx < ANCB) {
        // ---- anchor role: 1 anchor/thread, slim rcp-based IoU argmax ----
        const int a = bx * 256 + tid;          // 192*256 = 49152 >= NA
        const bool doA = a < NA;
        const int jb = j * NM;
        float4 an = anchors4[doA ? a : NA - 1];    // (y1,x1,y2,x2)
        const float ay1 = an.x, ax1 = an.y, ay2 = an.z, ax2 = an.w;
        const float aare = (ay2 - ay1) * (ax2 - ax1);

        float best = -1.0f;
        int bi = 0;
        #pragma unroll 16
        for (int m = 0; m < NM; ++m) {
            const float4 bm = boxes4[jb + m];      // x1,y1,x2,y2 (s_load)
            const int lab = labels[jb + m];
            const float bar = (bm.z - bm.x) * (bm.w - bm.y);
            const float bar_eff = (lab != 0) ? bar : __builtin_inff();
            float iw = fmaxf(fminf(ax2, bm.z) - fmaxf(ax1, bm.x), 0.0f);
            float ih = fmaxf(fminf(ay2, bm.w) - fmaxf(ay1, bm.y), 0.0f);
            float inter = iw * ih;
            float ua = (aare + bar_eff) - inter;   // >=100 valid, inf masked
            float iou = inter * __builtin_amdgcn_rcpf(ua);
            bool upd = iou > best;                 // strict > keeps first max
            best = upd ? iou : best;
            bi   = upd ? m : bi;
        }

        float corr = 0.0f, regl = 0.0f, npf = 0.0f;
        if (doA) {
            float4 bb = boxes4[jb + bi];
            int labg = labels[jb + bi];
            const float bar = (bb.z - bb.x) * (bb.w - bb.y);
            const float thr = (bar > 100.0f) ? 0.5f : 0.15f;
            if (best >= thr) {
                npf = 1.0f;
                const int al = labg - 1;   // label>=1 guaranteed when pos
                float p = cls[((size_t)j * NA + a) * NC + al];
                p = fminf(fmaxf(p, EPSF), 1.0f - EPSF);
                const float om = 1.0f - p;
                corr = 0.25f * om * om * (-__logf(p)) - 0.75f * p * p * (-__logf(om));

                const float aw = ax2 - ax1, ah = ay2 - ay1;
                const float acx = ax1 + 0.5f * aw, acy = ay1 + 0.5f * ah;
                float gw = bb.z - bb.x, gh = bb.w - bb.y;
                const float gcx = bb.x + 0.5f * gw, gcy = bb.y + 0.5f * gh;
                gw = fmaxf(gw, 1.0f);
                gh = fmaxf(gh, 1.0f);
                float4 r = reg[(size_t)j * NA + a];
                const float t0 = (gcy - acy) / ah;
                const float t1 = (gcx - acx) / aw;
                const float t2 = __logf(gh / ah);
                const float t3 = __logf(gw / aw);
                const float d0 = fabsf(t0 - r.x);
                const float d1 = fabsf(t1 - r.y);
                const float d2 = fabsf(t2 - r.z);
                const float d3 = fabsf(t3 - r.w);
                const float ninth = 1.0f / 9.0f;
                const float c = 0.5f / 9.0f;
                regl  = (d0 <= ninth) ? 4.5f * d0 * d0 : d0 - c;
                regl += (d1 <= ninth) ? 4.5f * d1 * d1 : d1 - c;
                regl += (d2 <= ninth) ? 4.5f * d2 * d2 : d2 - c;
                regl += (d3 <= ninth) ? 4.5f * d3 * d3 : d3 - c;
            }
        }
        corr = waveReduceSumF(corr);
        regl = waveReduceSumF(regl);
        npf  = waveReduceSumF(npf);
        const int wid = tid >> 6;
        if ((tid & 63) == 0) {
            sred[0][wid] = corr; sred[1][wid] = regl; sred[2][wid] = npf;
        }
        __syncthreads();
        if (tid == 0) {
            ws->corrp[j][bx] = sred[0][0] + sred[0][1] + sred[0][2] + sred[0][3];
            ws->regp[j][bx]  = sred[1][0] + sred[1][1] + sred[1][2] + sred[1][3];
            ws->npp[j][bx]   = sred[2][0] + sred[2][1] + sred[2][2] + sred[2][3];
        }
    } else {
        // ---- stream role: pure BW, 15-slot consume, 2-deep prefetch ----
        const int sbx = bx - ANCB;
        const int per4 = NA * NC / 4;          // 982080
        const int stride = STRB * 256;         // 65536
        const float4* base = cls4 + (size_t)j * per4;
        const int b = sbx * 256 + tid;

        float4 v = base[b];
        float4 vn = base[b + stride];
        float s0 = 0.0f, s1 = 0.0f, s2 = 0.0f, s3 = 0.0f;
        #pragma unroll
        for (int k = 0; k < 14; ++k) {
            float4 nx;
            if (k < 12) nx = base[b + (k + 2) * stride];
            CONSUME4(v);
            v = vn; vn = nx;
        }
        if (b < per4 - 14 * stride) {          // b < 64576
            float4 vt = base[b + 14 * stride];
            CONSUME4(vt);
        }
        float negs = NEG_SCALE * ((s0 + s1) + (s2 + s3));

        negs = waveReduceSumF(negs);
        const int wid = tid >> 6;
        if ((tid & 63) == 0) sred[0][wid] = negs;
        __syncthreads();
        if (tid == 0)
            ws->negp[j][sbx] = sred[0][0] + sred[0][1] + sred[0][2] + sred[0][3];
    }
}

// Finalize: 8 waves, wave w reduces image w's partials; thread 0 emits output.
__global__ void finalize_kernel(const Ws* __restrict__ ws, float* __restrict__ out) {
    __shared__ float scls[NB], sreg[NB];
    const int w = threadIdx.x >> 6;     // image
    const int lane = threadIdx.x & 63;
    float ns = 0.0f, cs = 0.0f, rs = 0.0f, np = 0.0f;
    #pragma unroll
    for (int i = lane; i < STRB; i += 64) ns += ws->negp[w][i];
    #pragma unroll
    for (int i = lane; i < ANCB; i += 64) {
        cs += ws->corrp[w][i];
        rs += ws->regp[w][i];
        np += ws->npp[w][i];
    }
    ns = waveReduceSumF(ns);
    cs = waveReduceSumF(cs);
    rs = waveReduceSumF(rs);
    np = waveReduceSumF(np);
    if (lane == 0) {
        float d = fmaxf(np, 1.0f);
        scls[w] = (ns + cs) / d;
        sreg[w] = (np > 0.0f) ? rs / (4.0f * d) : 0.0f;
    }
    __syncthreads();
    if (threadIdx.x == 0) {
        float acc = 0.0f, bsum = 0.0f;
        #pragma unroll
        for (int jj = 0; jj < NB; ++jj) { acc += scls[jj]; bsum += sreg[jj]; }
        out[0] = acc / (float)NB;
        out[1] = (bsum / (float)NB) * 50.0f;
    }
}

extern "C" void kernel_launch(void* const* d_in, const int* in_sizes, int n_in,
                              void* d_out, int out_size, void* d_ws, size_t ws_size,
                              hipStream_t stream) {
    const float* boxes   = (const float*)d_in[0];
    const int*   labels  = (const int*)d_in[1];
    const float* anchors = (const float*)d_in[2];
    const float* cls     = (const float*)d_in[3];
    const float* reg     = (const float*)d_in[4];
    float* out = (float*)d_out;
    Ws* ws = (Ws*)d_ws;

    dim3 g(ANCB + STRB, NB);
    main_kernel<<<g, 256, 0, stream>>>((const float4*)cls, cls,
                                       (const float4*)anchors, (const float4*)reg,
                                       (const float4*)boxes, labels, ws);

    finalize_kernel<<<1, 512, 0, stream>>>(ws, out);
}

// Round 20
// 33.727 us; speedup vs baseline: 1.1171x; 1.1171x over previous
//
#include <hip/hip_runtime.h>

// Problem constants (match reference setup_inputs)
#define NB 8
#define NM 64
#define NA 49104
#define NC 80
#define EPSF 1e-4f
#define BPI 256    // blocks per image (uniform role)
#define APB 192    // anchors per block (256*192 = 49152 >= 49104)

// Per-block partials; every slot written unconditionally -> no memset needed.
// Cross-kernel visibility via kernel boundary — no fences, no atomics.
// cnp = negs + corr merged (finalize sums them anyway).
struct Ws {
    float cnp[NB][BPI];
    float regp[NB][BPI];
    float npp[NB][BPI];
};

__device__ __forceinline__ float waveReduceSumF(float v) {
    #pragma unroll
    for (int off = 32; off > 0; off >>= 1) v += __shfl_down(v, off, 64);
    return v;
}

// Slim neg term: S = sum v^2 * log2(max(1-v, eps)); contribution -0.75*ln2*S.
#define NEG_SCALE (-0.51986038542f)   // -(0.75 * ln 2)

#define CONSUME4(V)                                                   \
    s0 = fmaf((V).x * (V).x, __log2f(fmaxf(1.0f - (V).x, EPSF)), s0); \
    s1 = fmaf((V).y * (V).y, __log2f(fmaxf(1.0f - (V).y, EPSF)), s1); \
    s2 = fmaf((V).z * (V).z, __log2f(fmaxf(1.0f - (V).z, EPSF)), s2); \
    s3 = fmaf((V).w * (V).w, __log2f(fmaxf(1.0f - (V).w, EPSF)), s3);

// Per-thread anchor work: IoU argmax over 64 boxes. Boxes/labels arrive via
// wave-uniform s_loads; masking is done on the SCALAR side (bar_eff = +inf
// for masked -> ua = inf -> iou = inter*rcp(inf) = 0 exactly; ties at 0 keep
// the first index and can never become pos since thr >= 0.15). rcp-based
// iou drops the bestu cross-multiply tracking entirely.
__device__ __forceinline__ void anchorWork(int j, int a, float4 an,
                                           const float4* __restrict__ boxes4,
                                           const int* __restrict__ labels,
                                           const float* __restrict__ cls,
                                           const float4* __restrict__ reg,
                                           float& corr, float& regl, float& npf) {
    const int jb = j * NM;
    const float ay1 = an.x, ax1 = an.y, ay2 = an.z, ax2 = an.w;  // (y1,x1,y2,x2)
    const float aare = (ay2 - ay1) * (ax2 - ax1);

    float best = -1.0f;
    int bi = 0;
    #pragma unroll 16
    for (int m = 0; m < NM; ++m) {
        // Uniform addresses -> s_load into SGPRs (free VALU operands).
        const float4 bm = boxes4[jb + m];      // x1,y1,x2,y2
        const int lab = labels[jb + m];
        const float bar = (bm.z - bm.x) * (bm.w - bm.y);
        // Scalar select (uniform inputs -> s_cselect, no per-lane op).
        const float bar_eff = (lab != 0) ? bar : __builtin_inff();
        float iw = fmaxf(fminf(ax2, bm.z) - fmaxf(ax1, bm.x), 0.0f);
        float ih = fmaxf(fminf(ay2, bm.w) - fmaxf(ay1, bm.y), 0.0f);
        float inter = iw * ih;
        float ua = (aare + bar_eff) - inter;   // inf for masked; >=100 valid
        float iou = inter * __builtin_amdgcn_rcpf(ua);
        bool upd = iou > best;                 // strict > keeps first max
        best = upd ? iou : best;
        bi   = upd ? m : bi;
    }

    float4 bb = boxes4[jb + bi];       // L2-hot 1 KB table
    int labg = labels[jb + bi];
    const float bar = (bb.z - bb.x) * (bb.w - bb.y);
    const bool big = bar > 100.0f;
    const float thr = big ? 0.5f : 0.15f;
    const bool pos = best >= thr;
    if (pos) {
        npf = 1.0f;
        const int al = labg - 1;       // label>=1 guaranteed when pos
        float p = cls[((size_t)j * NA + a) * NC + al];
        p = fminf(fmaxf(p, EPSF), 1.0f - EPSF);
        const float om = 1.0f - p;
        corr = 0.25f * om * om * (-__logf(p)) - 0.75f * p * p * (-__logf(om));

        const float aw = ax2 - ax1, ah = ay2 - ay1;
        const float acx = ax1 + 0.5f * aw, acy = ay1 + 0.5f * ah;
        float gw = bb.z - bb.x;
        float gh = bb.w - bb.y;
        const float gcx = bb.x + 0.5f * gw;
        const float gcy = bb.y + 0.5f * gh;
        gw = fmaxf(gw, 1.0f);
        gh = fmaxf(gh, 1.0f);
        float4 r = reg[(size_t)j * NA + a];
        const float t0 = (gcy - acy) / ah;
        const float t1 = (gcx - acx) / aw;
        const float t2 = __logf(gh / ah);
        const float t3 = __logf(gw / aw);
        const float d0 = fabsf(t0 - r.x);
        const float d1 = fabsf(t1 - r.y);
        const float d2 = fabsf(t2 - r.z);
        const float d3 = fabsf(t3 - r.w);
        const float ninth = 1.0f / 9.0f;
        const float c = 0.5f / 9.0f;
        regl  = (d0 <= ninth) ? 4.5f * d0 * d0 : d0 - c;
        regl += (d1 <= ninth) ? 4.5f * d1 * d1 : d1 - c;
        regl += (d2 <= ninth) ? 4.5f * d2 * d2 : d2 - c;
        regl += (d3 <= ninth) ? 4.5f * d3 * d3 : d3 - c;
    }
}

// Uniform-role kernel (R11 structure): anchor vector + 2 stream loads issued
// first, anchor VALU phase, then the neg-stream consume loop.
__global__ void main_kernel(const float4* __restrict__ cls4,
                            const float* __restrict__ cls,
                            const float4* __restrict__ anchors4,
                            const float4* __restrict__ reg,
                            const float4* __restrict__ boxes4,
                            const int* __restrict__ labels,
                            Ws* __restrict__ ws) {
    const int j = blockIdx.y;
    const int bx = blockIdx.x;
    const int tid = threadIdx.x;

    const int per4 = NA * NC / 4;          // 982080
    const int stride = BPI * 256;          // 65536
    const float4* base = cls4 + (size_t)j * per4;
    const int b = bx * 256 + tid;
    const int a = bx * APB + tid;
    const int ai = a < NA ? a : NA - 1;

    float4 an = anchors4[ai];              // oldest outstanding load
    float4 nv0 = base[b];
    float4 nv1 = base[b + stride];

    float corr = 0.0f, regl = 0.0f, npf = 0.0f;
    if (tid < APB && a < NA)
        anchorWork(j, a, an, boxes4, labels, cls, reg, corr, regl, npf);

    // ---- neg stream: consume 14 unconditional slots + tail ----
    float s0 = 0.0f, s1 = 0.0f, s2 = 0.0f, s3 = 0.0f;
    {
        float4 v = nv0, vn = nv1;
        #pragma unroll
        for (int k = 0; k < 14; ++k) {
            float4 nx;
            if (k < 12) nx = base[b + (k + 2) * stride];
            CONSUME4(v);
            v = vn; vn = nx;
        }
        if (b < per4 - 14 * stride) {      // b < 64576
            float4 vt = base[b + 14 * stride];
            CONSUME4(vt);
        }
    }
    float cn = fmaf(NEG_SCALE, (s0 + s1) + (s2 + s3), corr);

    // ---- block reduction & partial stores (3 values) ----
    __shared__ float sred[3][4];
    cn   = waveReduceSumF(cn);
    regl = waveReduceSumF(regl);
    npf  = waveReduceSumF(npf);
    const int wid = tid >> 6;
    if ((tid & 63) == 0) {
        sred[0][wid] = cn; sred[1][wid] = regl; sred[2][wid] = npf;
    }
    __syncthreads();
    if (tid == 0) {
        ws->cnp[j][bx]  = sred[0][0] + sred[0][1] + sred[0][2] + sred[0][3];
        ws->regp[j][bx] = sred[1][0] + sred[1][1] + sred[1][2] + sred[1][3];
        ws->npp[j][bx]  = sred[2][0] + sred[2][1] + sred[2][2] + sred[2][3];
    }
}

// Finalize: 8 waves, wave w reduces image w's partials; thread 0 emits output.
__global__ void finalize_kernel(const Ws* __restrict__ ws, float* __restrict__ out) {
    __shared__ float scls[NB], sreg[NB];
    const int w = threadIdx.x >> 6;     // image
    const int lane = threadIdx.x & 63;
    float cs = 0.0f, rs = 0.0f, np = 0.0f;
    #pragma unroll
    for (int i = lane; i < BPI; i += 64) {
        cs += ws->cnp[w][i];
        rs += ws->regp[w][i];
        np += ws->npp[w][i];
    }
    cs = waveReduceSumF(cs);
    rs = waveReduceSumF(rs);
    np = waveReduceSumF(np);
    if (lane == 0) {
        float d = fmaxf(np, 1.0f);
        scls[w] = cs / d;
        sreg[w] = (np > 0.0f) ? rs / (4.0f * d) : 0.0f;
    }
    __syncthreads();
    if (threadIdx.x == 0) {
        float acc = 0.0f, bsum = 0.0f;
        #pragma unroll
        for (int jj = 0; jj < NB; ++jj) { acc += scls[jj]; bsum += sreg[jj]; }
        out[0] = acc / (float)NB;
        out[1] = (bsum / (float)NB) * 50.0f;
    }
}

extern "C" void kernel_launch(void* const* d_in, const int* in_sizes, int n_in,
                              void* d_out, int out_size, void* d_ws, size_t ws_size,
                              hipStream_t stream) {
    const float* boxes   = (const float*)d_in[0];
    const int*   labels  = (const int*)d_in[1];
    const float* anchors = (const float*)d_in[2];
    const float* cls     = (const float*)d_in[3];
    const float* reg     = (const float*)d_in[4];
    float* out = (float*)d_out;
    Ws* ws = (Ws*)d_ws;

    dim3 g(BPI, NB);
    main_kernel<<<g, 256, 0, stream>>>((const float4*)cls, cls,
                                       (const float4*)anchors, (const float4*)reg,
                                       (const float4*)boxes, labels, ws);

    finalize_kernel<<<1, 512, 0, stream>>>(ws, out);
}